// Round 1
// baseline (136.786 us; speedup 1.0000x reference)
//
#include <hip/hip_runtime.h>
#include <math.h>

#define NBINS 256
#define NB    4096            // fine order-statistic buckets
#define BLK   256
#define CHUNK (NB / BLK)      // 16

__global__ __launch_bounds__(BLK) void hist_match_kernel(
    const float* __restrict__ x,      // [C, N]
    const float* __restrict__ masks,  // [S, N]
    const float* __restrict__ thist,  // [S, C, 256]
    const float* __restrict__ tmins,  // [S, C]
    const float* __restrict__ tmaxs,  // [S, C]
    float* __restrict__ out,          // [1 + S*C*256]
    float* __restrict__ ws,           // [S*C] per-channel loss partials
    int C, int N)
{
    const int sc = blockIdx.x;
    const int s = sc / C;
    const int c = sc - s * C;
    const float* __restrict__ xc = x + (size_t)c * N;
    const float* __restrict__ mk = masks + (size_t)s * N;
    const int tid = threadIdx.x;
    const int lane = tid & 63;

    __shared__ unsigned int cnt[NB + 1];
    __shared__ float        fsum[NB + 1];
    __shared__ unsigned int hist[NBINS];
    __shared__ float cdfA[NBINS], cdfB[NBINS];
    __shared__ float Sarr[NBINS];
    __shared__ int   Karr[NBINS];
    __shared__ float redA[BLK], redB[BLK];
    __shared__ unsigned int scA[BLK], scB[BLK];
    __shared__ float ssA[BLK], ssB[BLK];
    __shared__ unsigned int zcnt;
    __shared__ float stats[3];   // lo, hi, sumsq

    // ---------- Phase A: min / max / sum of squares ----------
    float vmin = 3.4e38f, vmax = -3.4e38f;
    float ssq = 0.f;
    for (int i = tid * 4; i < N; i += BLK * 4) {
        const float4 xv = *reinterpret_cast<const float4*>(xc + i);
        const float4 mv = *reinterpret_cast<const float4*>(mk + i);
        const float v0 = xv.x * mv.x, v1 = xv.y * mv.y;
        const float v2 = xv.z * mv.z, v3 = xv.w * mv.w;
        vmin = fminf(vmin, fminf(fminf(v0, v1), fminf(v2, v3)));
        vmax = fmaxf(vmax, fmaxf(fmaxf(v0, v1), fmaxf(v2, v3)));
        ssq += v0 * v0 + v1 * v1 + v2 * v2 + v3 * v3;
    }
    redA[tid] = vmin; redB[tid] = vmax;
    __syncthreads();
    for (int st = BLK / 2; st > 0; st >>= 1) {
        if (tid < st) {
            redA[tid] = fminf(redA[tid], redA[tid + st]);
            redB[tid] = fmaxf(redB[tid], redB[tid + st]);
        }
        __syncthreads();
    }
    if (tid == 0) { stats[0] = redA[0]; stats[1] = redB[0]; }
    __syncthreads();
    redA[tid] = ssq;
    __syncthreads();
    for (int st = BLK / 2; st > 0; st >>= 1) {
        if (tid < st) redA[tid] += redA[tid + st];
        __syncthreads();
    }
    if (tid == 0) stats[2] = redA[0];

    // init LDS for phase B
    for (int i = tid; i < NB + 1; i += BLK) { cnt[i] = 0u; fsum[i] = 0.f; }
    for (int i = tid; i < NBINS; i += BLK) hist[i] = 0u;
    if (tid == 0) zcnt = 0u;
    __syncthreads();

    const float lo  = stats[0];
    const float hi  = stats[1];
    const float rng = fmaxf(hi - lo, 1e-12f);
    const float sch = 255.0f / rng;          // reference hist scale
    const float scb = (float)NB / rng;       // fine bucket scale
    const int ib0 = min(NBINS - 1, max(0, (int)floorf((0.0f - lo) * sch + 0.5f)));
    const int b0  = min(NB - 1,    max(0, (int)floorf((0.0f - lo) * scb)));

    // ---------- Phase B: histogram + fine buckets ----------
    for (int i = tid * 4; i < N; i += BLK * 4) {
        const float4 xv = *reinterpret_cast<const float4*>(xc + i);
        const float4 mv = *reinterpret_cast<const float4*>(mk + i);
        const float vv[4] = { xv.x * mv.x, xv.y * mv.y, xv.z * mv.z, xv.w * mv.w };
        #pragma unroll
        for (int e = 0; e < 4; ++e) {
            const float v = vv[e];
            const bool isz = (v == 0.0f);
            const unsigned long long mz = __ballot(isz);
            if (!isz) {
                const int ib = min(NBINS - 1, max(0, (int)floorf((v - lo) * sch + 0.5f)));
                atomicAdd(&hist[ib], 1u);
                const int jb = min(NB - 1, max(0, (int)floorf((v - lo) * scb)));
                atomicAdd(&cnt[jb], 1u);
                atomicAdd(&fsum[jb], v);
            }
            if (lane == 0) {   // wave-aggregated add for the zero spike
                const unsigned nz = (unsigned)__popcll(mz);
                if (nz) { atomicAdd(&hist[ib0], nz); atomicAdd(&zcnt, nz); }
            }
        }
    }
    __syncthreads();

    // write hist output (float counts)
    {
        float* ho = out + 1 + (size_t)sc * NBINS;
        for (int i = tid; i < NBINS; i += BLK) ho[i] = (float)hist[i];
    }

    // ---------- target CDF (BLK == NBINS) ----------
    const float th = thist[(size_t)sc * NBINS + tid];
    redA[tid] = th;
    __syncthreads();
    for (int st = BLK / 2; st > 0; st >>= 1) {
        if (tid < st) redA[tid] += redA[tid + st];
        __syncthreads();
    }
    const float tsum = redA[0];
    const float tval = th * ((float)N / fmaxf(tsum, 1e-12f));
    float* srcp = cdfA; float* dstp = cdfB;
    srcp[tid] = tval;
    __syncthreads();
    for (int off = 1; off < NBINS; off <<= 1) {   // Hillis-Steele inclusive scan
        float v = srcp[tid];
        if (tid >= off) v += srcp[tid - off];
        dstp[tid] = v;
        __syncthreads();
        float* tp = srcp; srcp = dstp; dstp = tp;
    }
    {
        // K_b = #{r in [0,N): r + 0.5 <= cdf[b]}
        const float cdfv = srcp[tid];
        int K = (int)floorf(cdfv - 0.5f) + 1;
        K = min(N, max(0, K));
        if (tid == NBINS - 1) K = N;   // bin 255 runs to N (clip of searchsorted)
        Karr[tid] = K;
    }

    // ---------- Phase C: exclusive prefix over buckets (in place) ----------
    const int base = tid * CHUNK;
    unsigned cacc = 0u; float sacc = 0.f;
    #pragma unroll
    for (int i = 0; i < CHUNK; ++i) {
        const unsigned cc = cnt[base + i];
        const float    sv = fsum[base + i];
        cnt[base + i] = cacc; fsum[base + i] = sacc;
        cacc += cc; sacc += sv;
    }
    scA[tid] = cacc; ssA[tid] = sacc;
    __syncthreads();
    {
        unsigned* cs = scA; unsigned* cd = scB;
        float* fs = ssA; float* fd = ssB;
        for (int off = 1; off < BLK; off <<= 1) {
            unsigned cv = cs[tid]; float fv = fs[tid];
            if (tid >= off) { cv += cs[tid - off]; fv += fs[tid - off]; }
            cd[tid] = cv; fd[tid] = fv;
            __syncthreads();
            unsigned* t1 = cs; cs = cd; cd = t1;
            float*    t2 = fs; fs = fd; fd = t2;
        }
        const unsigned cofs = cs[tid] - cacc;   // exclusive offset for this chunk
        const float    sofs = fs[tid] - sacc;
        for (int i = 0; i < CHUNK; ++i) { cnt[base + i] += cofs; fsum[base + i] += sofs; }
        if (tid == BLK - 1) { cnt[NB] = cs[tid]; fsum[NB] = fs[tid]; }  // sentinels
    }
    __syncthreads();

    // ---------- S(K) lookups: sum of k smallest values ----------
    {
        const unsigned n0 = zcnt;       // exact-zero class, ordered just before bucket b0
        const unsigned Z0 = cnt[b0];
        const float   SZ0 = fsum[b0];
        const unsigned uk = (unsigned)Karr[tid];
        float Sv;
        if (uk <= Z0) {
            int jlo = 0, jhi = b0;
            while (jlo < jhi) {
                const int mid = (jlo + jhi + 1) >> 1;
                if (cnt[mid] <= uk) jlo = mid; else jhi = mid - 1;
            }
            const unsigned d = uk - cnt[jlo];
            Sv = fsum[jlo];
            if (d) Sv += (float)d * (fsum[jlo + 1] - fsum[jlo]) / (float)(cnt[jlo + 1] - cnt[jlo]);
        } else if (uk <= Z0 + n0) {
            Sv = SZ0;                   // zeros contribute 0 to the sum
        } else {
            const unsigned uk2 = uk - n0;
            int jlo = b0, jhi = NB;
            while (jlo < jhi) {
                const int mid = (jlo + jhi + 1) >> 1;
                if (cnt[mid] <= uk2) jlo = mid; else jhi = mid - 1;
            }
            const unsigned d = uk2 - cnt[jlo];
            Sv = fsum[jlo];
            if (d) Sv += (float)d * (fsum[jlo + 1] - fsum[jlo]) / (float)(cnt[jlo + 1] - cnt[jlo]);
        }
        if (tid == NBINS - 1) Sv = fsum[NB];   // S(N) = total sum (zeros add 0)
        Sarr[tid] = Sv;
    }
    __syncthreads();

    // ---------- loss terms ----------
    {
        const float tmn = tmins[sc];
        const float tmx = tmaxs[sc];
        const float Tb = ((float)tid / 255.0f) * (tmx - tmn) + tmn;
        const float Sb = Sarr[tid];
        const float Sp = (tid == 0) ? 0.f : Sarr[tid - 1];
        const int   Kb = Karr[tid];
        const int   Kp = (tid == 0) ? 0 : Karr[tid - 1];
        redA[tid] = -2.0f * Tb * (Sb - Sp) + Tb * Tb * (float)(Kb - Kp);
    }
    __syncthreads();
    for (int st = BLK / 2; st > 0; st >>= 1) {
        if (tid < st) redA[tid] += redA[tid + st];
        __syncthreads();
    }
    if (tid == 0) ws[sc] = (stats[2] + redA[0]) / ((float)C * (float)N);
}

__global__ void reduce_loss_kernel(const float* __restrict__ ws,
                                   float* __restrict__ out, int n)
{
    __shared__ float sh[256];
    const int tid = threadIdx.x;
    float v = 0.f;
    for (int i = tid; i < n; i += 256) v += ws[i];
    sh[tid] = v;
    __syncthreads();
    for (int st = 128; st > 0; st >>= 1) {
        if (tid < st) sh[tid] += sh[tid + st];
        __syncthreads();
    }
    if (tid == 0) out[0] = sh[0];
}

extern "C" void kernel_launch(void* const* d_in, const int* in_sizes, int n_in,
                              void* d_out, int out_size, void* d_ws, size_t ws_size,
                              hipStream_t stream)
{
    const float* x     = (const float*)d_in[0];   // [1,C,H,W]
    const float* masks = (const float*)d_in[1];   // [S,H,W]
    const float* thist = (const float*)d_in[2];   // [S,C,256]
    const float* tmins = (const float*)d_in[3];   // [S,C]
    const float* tmaxs = (const float*)d_in[4];   // [S,C]
    float* out = (float*)d_out;
    float* ws  = (float*)d_ws;

    // derive shapes: SC = S*C, C/S = in_sizes[0]/in_sizes[1]
    const int SC = in_sizes[3];
    const long long ratio = (long long)in_sizes[0] / (long long)in_sizes[1];
    const long long csq   = (long long)SC * ratio;
    const int C = (int)(sqrt((double)csq) + 0.5);
    const int S = SC / C;
    const int N = in_sizes[1] / S;

    hist_match_kernel<<<SC, BLK, 0, stream>>>(x, masks, thist, tmins, tmaxs, out, ws, C, N);
    reduce_loss_kernel<<<1, 256, 0, stream>>>(ws, out, SC);
}

// Round 2
// 119.063 us; speedup vs baseline: 1.1489x; 1.1489x over previous
//
#include <hip/hip_runtime.h>
#include <math.h>

#define NBINS 256
#define NB    4096            // fine order-statistic buckets (16x refinement of hist grid)
#define BLK   1024
#define CHUNK (NB / BLK)      // 4

__global__ __launch_bounds__(BLK) void hist_match_kernel(
    const float* __restrict__ x,      // [C, N]
    const float* __restrict__ masks,  // [S, N]
    const float* __restrict__ thist,  // [S, C, 256]
    const float* __restrict__ tmins,  // [S, C]
    const float* __restrict__ tmaxs,  // [S, C]
    float* __restrict__ out,          // [1 + S*C*256]
    float* __restrict__ ws,           // [S*C] per-channel loss partials
    int C, int N)
{
    const int sc = blockIdx.x;
    const int s = sc / C;
    const int c = sc - s * C;
    const float* __restrict__ xc = x + (size_t)c * N;
    const float* __restrict__ mk = masks + (size_t)s * N;
    const int tid = threadIdx.x;

    __shared__ unsigned int cnt[NB + 1];
    __shared__ float        fsum[NB + 1];
    __shared__ float cdfA[NBINS], cdfB[NBINS];
    __shared__ float Sarr[NBINS];
    __shared__ int   Karr[NBINS];
    __shared__ float redA[BLK], redB[BLK];
    __shared__ unsigned int scA[BLK], scB[BLK];
    __shared__ float ssA[BLK], ssB[BLK];
    __shared__ float stats[3];   // lo, hi, sumsq

    // ---------- Phase A: min / max / sum of squares ----------
    float vmin = 3.4e38f, vmax = -3.4e38f;
    float ssq = 0.f;
    for (int i = tid * 4; i < N; i += BLK * 4) {
        const float4 xv = *reinterpret_cast<const float4*>(xc + i);
        const float4 mv = *reinterpret_cast<const float4*>(mk + i);
        const float v0 = xv.x * mv.x, v1 = xv.y * mv.y;
        const float v2 = xv.z * mv.z, v3 = xv.w * mv.w;
        vmin = fminf(vmin, fminf(fminf(v0, v1), fminf(v2, v3)));
        vmax = fmaxf(vmax, fmaxf(fmaxf(v0, v1), fmaxf(v2, v3)));
        ssq += v0 * v0 + v1 * v1 + v2 * v2 + v3 * v3;
    }
    redA[tid] = vmin; redB[tid] = vmax;
    __syncthreads();
    for (int st = BLK / 2; st > 0; st >>= 1) {
        if (tid < st) {
            redA[tid] = fminf(redA[tid], redA[tid + st]);
            redB[tid] = fmaxf(redB[tid], redB[tid + st]);
        }
        __syncthreads();
    }
    if (tid == 0) { stats[0] = redA[0]; stats[1] = redB[0]; }
    __syncthreads();
    redA[tid] = ssq;
    __syncthreads();
    for (int st = BLK / 2; st > 0; st >>= 1) {
        if (tid < st) redA[tid] += redA[tid + st];
        __syncthreads();
    }
    if (tid == 0) stats[2] = redA[0];

    // init LDS for phase B
    for (int i = tid; i < NB + 1; i += BLK) { cnt[i] = 0u; fsum[i] = 0.f; }
    __syncthreads();

    const float lo  = stats[0];
    const float hi  = stats[1];
    const float rng = fmaxf(hi - lo, 1e-12f);
    const float sch  = 255.0f / rng;           // reference hist scale
    const float sc16 = 4080.0f / rng;          // fine grid = 16x the rounded hist grid
    const int ib0 = min(NBINS - 1, max(0, (int)floorf((0.0f - lo) * sch + 0.5f)));
    const int b0  = min(NB - 1,    max(0, (int)floorf((0.0f - lo) * sc16 + 8.0f)));

    // ---------- Phase B: fine buckets (hist derived later) ----------
    unsigned zloc = 0u;
    for (int i = tid * 4; i < N; i += BLK * 4) {
        const float4 xv = *reinterpret_cast<const float4*>(xc + i);
        const float4 mv = *reinterpret_cast<const float4*>(mk + i);
        const float vv[4] = { xv.x * mv.x, xv.y * mv.y, xv.z * mv.z, xv.w * mv.w };
        #pragma unroll
        for (int e = 0; e < 4; ++e) {
            const float v = vv[e];
            if (v == 0.0f) {
                ++zloc;
            } else {
                const int jb = min(NB - 1, max(0, (int)floorf((v - lo) * sc16 + 8.0f)));
                atomicAdd(&cnt[jb], 1u);
                atomicAdd(&fsum[jb], v);
            }
        }
    }
    __syncthreads();

    // zero-spike count reduce (register -> scA -> broadcast)
    scA[tid] = zloc;
    __syncthreads();
    for (int st = BLK / 2; st > 0; st >>= 1) {
        if (tid < st) scA[tid] += scA[tid + st];
        __syncthreads();
    }
    const unsigned n0 = scA[0];
    __syncthreads();

    // ---------- target CDF (256 bins, guarded to tid<256) ----------
    float th = 0.f;
    if (tid < NBINS) th = thist[(size_t)sc * NBINS + tid];
    redA[tid] = th;
    __syncthreads();
    for (int st = BLK / 2; st > 0; st >>= 1) {
        if (tid < st) redA[tid] += redA[tid + st];
        __syncthreads();
    }
    const float tsum = redA[0];
    __syncthreads();
    {
        float* srcp = cdfA; float* dstp = cdfB;
        if (tid < NBINS) srcp[tid] = th * ((float)N / fmaxf(tsum, 1e-12f));
        __syncthreads();
        for (int off = 1; off < NBINS; off <<= 1) {   // Hillis-Steele inclusive scan
            if (tid < NBINS) {
                float v = srcp[tid];
                if (tid >= off) v += srcp[tid - off];
                dstp[tid] = v;
            }
            __syncthreads();
            float* tp = srcp; srcp = dstp; dstp = tp;
        }
        if (tid < NBINS) {
            // K_b = #{r in [0,N): r + 0.5 <= cdf[b]}
            const float cdfv = srcp[tid];
            int K = (int)floorf(cdfv - 0.5f) + 1;
            K = min(N, max(0, K));
            if (tid == NBINS - 1) K = N;   // bin 255 runs to N (clip of searchsorted)
            Karr[tid] = K;
        }
    }
    __syncthreads();

    // ---------- Phase C: exclusive prefix over buckets (in place) ----------
    const int base = tid * CHUNK;
    unsigned cacc = 0u; float sacc = 0.f;
    #pragma unroll
    for (int i = 0; i < CHUNK; ++i) {
        const unsigned cc = cnt[base + i];
        const float    sv = fsum[base + i];
        cnt[base + i] = cacc; fsum[base + i] = sacc;
        cacc += cc; sacc += sv;
    }
    scA[tid] = cacc; ssA[tid] = sacc;
    __syncthreads();
    {
        unsigned* cs = scA; unsigned* cd = scB;
        float* fs = ssA; float* fd = ssB;
        for (int off = 1; off < BLK; off <<= 1) {
            unsigned cv = cs[tid]; float fv = fs[tid];
            if (tid >= off) { cv += cs[tid - off]; fv += fs[tid - off]; }
            cd[tid] = cv; fd[tid] = fv;
            __syncthreads();
            unsigned* t1 = cs; cs = cd; cd = t1;
            float*    t2 = fs; fs = fd; fd = t2;
        }
        const unsigned cofs = cs[tid] - cacc;   // exclusive offset for this chunk
        const float    sofs = fs[tid] - sacc;
        for (int i = 0; i < CHUNK; ++i) { cnt[base + i] += cofs; fsum[base + i] += sofs; }
        if (tid == BLK - 1) { cnt[NB] = cs[tid]; fsum[NB] = fs[tid]; }  // sentinels
    }
    __syncthreads();

    // ---------- hist output derived from bucket prefix (16 buckets per bin) ----------
    if (tid < NBINS) {
        unsigned h = cnt[16 * tid + 16] - cnt[16 * tid];
        if (tid == ib0) h += n0;
        out[1 + (size_t)sc * NBINS + tid] = (float)h;
    }

    // ---------- S(K) lookups: sum of k smallest values ----------
    if (tid < NBINS) {
        const unsigned Z0 = cnt[b0];     // nonzeros strictly below zero's bucket
        const float   SZ0 = fsum[b0];
        const unsigned uk = (unsigned)Karr[tid];
        float Sv;
        if (uk <= Z0) {
            int jlo = 0, jhi = b0;
            while (jlo < jhi) {
                const int mid = (jlo + jhi + 1) >> 1;
                if (cnt[mid] <= uk) jlo = mid; else jhi = mid - 1;
            }
            const unsigned d = uk - cnt[jlo];
            Sv = fsum[jlo];
            if (d) Sv += (float)d * (fsum[jlo + 1] - fsum[jlo]) / (float)(cnt[jlo + 1] - cnt[jlo]);
        } else if (uk <= Z0 + n0) {
            Sv = SZ0;                   // zeros contribute 0 to the sum
        } else {
            const unsigned uk2 = uk - n0;
            int jlo = b0, jhi = NB;
            while (jlo < jhi) {
                const int mid = (jlo + jhi + 1) >> 1;
                if (cnt[mid] <= uk2) jlo = mid; else jhi = mid - 1;
            }
            const unsigned d = uk2 - cnt[jlo];
            Sv = fsum[jlo];
            if (d) Sv += (float)d * (fsum[jlo + 1] - fsum[jlo]) / (float)(cnt[jlo + 1] - cnt[jlo]);
        }
        if (tid == NBINS - 1) Sv = fsum[NB];   // S(N) = total sum (zeros add 0)
        Sarr[tid] = Sv;
    }
    __syncthreads();

    // ---------- loss terms ----------
    if (tid < NBINS) {
        const float tmn = tmins[sc];
        const float tmx = tmaxs[sc];
        const float Tb = ((float)tid / 255.0f) * (tmx - tmn) + tmn;
        const float Sb = Sarr[tid];
        const float Sp = (tid == 0) ? 0.f : Sarr[tid - 1];
        const int   Kb = Karr[tid];
        const int   Kp = (tid == 0) ? 0 : Karr[tid - 1];
        redA[tid] = -2.0f * Tb * (Sb - Sp) + Tb * Tb * (float)(Kb - Kp);
    } else {
        redA[tid] = 0.f;
    }
    __syncthreads();
    for (int st = BLK / 2; st > 0; st >>= 1) {
        if (tid < st) redA[tid] += redA[tid + st];
        __syncthreads();
    }
    if (tid == 0) ws[sc] = (stats[2] + redA[0]) / ((float)C * (float)N);
}

__global__ void reduce_loss_kernel(const float* __restrict__ ws,
                                   float* __restrict__ out, int n)
{
    __shared__ float sh[256];
    const int tid = threadIdx.x;
    float v = 0.f;
    for (int i = tid; i < n; i += 256) v += ws[i];
    sh[tid] = v;
    __syncthreads();
    for (int st = 128; st > 0; st >>= 1) {
        if (tid < st) sh[tid] += sh[tid + st];
        __syncthreads();
    }
    if (tid == 0) out[0] = sh[0];
}

extern "C" void kernel_launch(void* const* d_in, const int* in_sizes, int n_in,
                              void* d_out, int out_size, void* d_ws, size_t ws_size,
                              hipStream_t stream)
{
    const float* x     = (const float*)d_in[0];   // [1,C,H,W]
    const float* masks = (const float*)d_in[1];   // [S,H,W]
    const float* thist = (const float*)d_in[2];   // [S,C,256]
    const float* tmins = (const float*)d_in[3];   // [S,C]
    const float* tmaxs = (const float*)d_in[4];   // [S,C]
    float* out = (float*)d_out;
    float* ws  = (float*)d_ws;

    // derive shapes: SC = S*C, C/S = in_sizes[0]/in_sizes[1]
    const int SC = in_sizes[3];
    const long long ratio = (long long)in_sizes[0] / (long long)in_sizes[1];
    const long long csq   = (long long)SC * ratio;
    const int C = (int)(sqrt((double)csq) + 0.5);
    const int S = SC / C;
    const int N = in_sizes[1] / S;

    hist_match_kernel<<<SC, BLK, 0, stream>>>(x, masks, thist, tmins, tmaxs, out, ws, C, N);
    reduce_loss_kernel<<<1, 256, 0, stream>>>(ws, out, SC);
}